// Round 9
// baseline (214.144 us; speedup 1.0000x reference)
//
#include <hip/hip_runtime.h>
#include <hip/hip_bf16.h>
#include <math.h>

typedef __bf16 bf16_t;
typedef __bf16 bf16x2 __attribute__((ext_vector_type(2)));
typedef __bf16 bf16x4 __attribute__((ext_vector_type(4)));
typedef __bf16 bf16x8 __attribute__((ext_vector_type(8)));
typedef float floatx4 __attribute__((ext_vector_type(4)));

constexpr int N_ = 4, L_ = 2048, S_ = 2048, H_ = 8, D_ = 64;

// ---------------------------------------------------------------------------
// prologue: K fp32 [n,s,h,d] -> bf16 Kb [nh,s,d]; V fp32 -> bf16 Vtb [nh,d,s]
__global__ __launch_bounds__(256)
void prep(const float* __restrict__ Kg, const float* __restrict__ Vg,
          bf16_t* __restrict__ Kb, bf16_t* __restrict__ Vtb) {
  __shared__ bf16x2 pr_sh[64 * 33];
  const int tid = threadIdx.x;
  const int nh = blockIdx.y, s0 = blockIdx.x * 64;
  const int n = nh >> 3, h = nh & 7;
  {
    const int srow = tid >> 2, d0 = (tid & 3) * 16;
    const float* kp = Kg + (((size_t)n * S_ + s0 + srow) * H_ + h) * D_ + d0;
    float4 x0 = ((const float4*)kp)[0], x1 = ((const float4*)kp)[1];
    float4 x2 = ((const float4*)kp)[2], x3 = ((const float4*)kp)[3];
    bf16x8 f0, f1;
    f0[0] = (bf16_t)x0.x; f0[1] = (bf16_t)x0.y; f0[2] = (bf16_t)x0.z; f0[3] = (bf16_t)x0.w;
    f0[4] = (bf16_t)x1.x; f0[5] = (bf16_t)x1.y; f0[6] = (bf16_t)x1.z; f0[7] = (bf16_t)x1.w;
    f1[0] = (bf16_t)x2.x; f1[1] = (bf16_t)x2.y; f1[2] = (bf16_t)x2.z; f1[3] = (bf16_t)x2.w;
    f1[4] = (bf16_t)x3.x; f1[5] = (bf16_t)x3.y; f1[6] = (bf16_t)x3.z; f1[7] = (bf16_t)x3.w;
    *(bf16x8*)&Kb[((size_t)nh * S_ + s0 + srow) * D_ + d0] = f0;
    *(bf16x8*)&Kb[((size_t)nh * S_ + s0 + srow) * D_ + d0 + 8] = f1;
  }
  {
    const int s2 = tid >> 3;
    const int dg = (tid & 7) * 8;
    const float* vp0 = Vg + (((size_t)n * S_ + s0 + 2 * s2) * H_ + h) * D_ + dg;
    const float* vp1 = vp0 + (size_t)H_ * D_;
    float4 a0 = ((const float4*)vp0)[0], a1 = ((const float4*)vp0)[1];
    float4 b0 = ((const float4*)vp1)[0], b1 = ((const float4*)vp1)[1];
    float r0[8] = { a0.x, a0.y, a0.z, a0.w, a1.x, a1.y, a1.z, a1.w };
    float r1[8] = { b0.x, b0.y, b0.z, b0.w, b1.x, b1.y, b1.z, b1.w };
#pragma unroll
    for (int j = 0; j < 8; ++j) {
      bf16x2 pr; pr[0] = (bf16_t)r0[j]; pr[1] = (bf16_t)r1[j];
      pr_sh[(dg + j) * 33 + s2] = pr;
    }
  }
  __syncthreads();
  {
    const int dr = tid >> 2, sq = tid & 3;
    bf16x8 o0, o1;
#pragma unroll
    for (int p = 0; p < 4; ++p) {
      bf16x2 v = pr_sh[dr * 33 + sq * 8 + p];
      o0[2 * p] = v[0]; o0[2 * p + 1] = v[1];
    }
#pragma unroll
    for (int p = 0; p < 4; ++p) {
      bf16x2 v = pr_sh[dr * 33 + sq * 8 + 4 + p];
      o1[2 * p] = v[0]; o1[2 * p + 1] = v[1];
    }
    bf16_t* op = &Vtb[((size_t)nh * D_ + dr) * S_ + s0 + sq * 16];
    *(bf16x8*)op = o0;
    *(bf16x8*)(op + 8) = o1;
  }
}

// ---------------------------------------------------------------------------
// fattn r18: LDS-free, barrier-free. Seven schedule variants (r12-r17) all
// landed at 49-55us / 21-27% MfmaUtil; even barrier-free r0 sat at 22% ->
// the invariant limiter is the K/V LDS round-trip on the critical path of
// a 2-wave/SIMD kernel, not phase alignment. prep's layouts make every
// MFMA fragment 16 CONTIGUOUS bytes in global memory (Kb[s][d]: kf at
// row s0+mb*16+l16, col kc*32+quad*8; Vtb[d][s]: vf at row nbd*16+l16,
// col s0+pp*32+quad*8), lanes forming 64B segments -> coalesced L2 reads;
// per-chunk 16KB working set is L1-sized and shared by 8 waves; per-XCD
// K/V footprint 2MB < 4MB L2. So fragments load global->VGPR directly:
// no smem, no DMA, no s_barrier in the whole loop. Two-chunk register
// double-buffer (named A/B sets, 2x-unrolled loop, rule #20) gives each
// prefetch a full compute body (~1300cyc) of latency cover via the
// compiler's counted vmcnt. Numerics bit-identical to r17 (same fragment
// values, same MFMA order). setprio kept: independent-wave regime is
// T5's proven +4-7% attn case (m191).
__global__ __launch_bounds__(512, 2)
void fattn(const float* __restrict__ Qg, const bf16_t* __restrict__ Kb,
           const bf16_t* __restrict__ Vtb, float* __restrict__ Og) {
  const int tid  = threadIdx.x;
  const int wave = tid >> 6;
  const int lane = tid & 63;
  const int quad = lane >> 4;
  const int l16  = lane & 15;

  // XCD mapping: 256 blocks, lb&7 = XCD; nh = lb&31 -> nh's 8 q-blocks all
  // on XCD nh&7; each XCD serves 4 nh x 512KB bf16 K/V from its L2.
  const int lb = blockIdx.x;
  const int nh = lb & 31;
  const int qb = lb >> 5;                    // 0..7
  const int n  = nh >> 3;
  const int h  = nh & 7;
  const int qrow0 = qb * 256 + wave * 32;    // wave owns 32 q rows

  // ---- Q B-frags (B[k=d][n=q]: n=l16, k=quad*8+j), scale*log2e folded ----
  const float qs = 0.125f * 1.44269504088896340736f;
  bf16x8 qf[2][2];
#pragma unroll
  for (int nbq = 0; nbq < 2; ++nbq)
#pragma unroll
    for (int kc = 0; kc < 2; ++kc) {
      const float* p = Qg +
          (((size_t)n * L_ + qrow0 + nbq * 16 + l16) * H_ + h) * D_ +
          kc * 32 + quad * 8;
      float4 a = ((const float4*)p)[0];
      float4 b = ((const float4*)p)[1];
      bf16x8 f;
      f[0] = (bf16_t)(a.x * qs); f[1] = (bf16_t)(a.y * qs);
      f[2] = (bf16_t)(a.z * qs); f[3] = (bf16_t)(a.w * qs);
      f[4] = (bf16_t)(b.x * qs); f[5] = (bf16_t)(b.y * qs);
      f[6] = (bf16_t)(b.z * qs); f[7] = (bf16_t)(b.w * qs);
      qf[nbq][kc] = f;
    }

  floatx4 oacc[2][4];
#pragma unroll
  for (int a = 0; a < 2; ++a)
#pragma unroll
    for (int b = 0; b < 4; ++b) oacc[a][b] = (floatx4){0.f, 0.f, 0.f, 0.f};
  float lsum_[2] = {0.f, 0.f};

  const bf16_t* kbase = Kb + (size_t)nh * S_ * D_;
  const bf16_t* vbase = Vtb + (size_t)nh * D_ * S_;

  // fragment register sets (double-buffered across chunks)
  struct Frags { bf16x8 k[4][2]; bf16x8 v[4][2]; };

  auto load_frags = [&](Frags& F, int t) {
    const int s0 = t * 64;
#pragma unroll
    for (int mb = 0; mb < 4; ++mb)
#pragma unroll
      for (int kc = 0; kc < 2; ++kc)
        F.k[mb][kc] = *(const bf16x8*)
            &kbase[(size_t)(s0 + mb * 16 + l16) * 64 + kc * 32 + quad * 8];
#pragma unroll
    for (int nbd = 0; nbd < 4; ++nbd)
#pragma unroll
      for (int pp = 0; pp < 2; ++pp)
        F.v[nbd][pp] = *(const bf16x8*)
            &vbase[(size_t)(nbd * 16 + l16) * S_ + s0 + pp * 32 + quad * 8];
  };

  auto compute = [&](Frags& F) {
    // QK MFMA cluster
    floatx4 sacc[4][2];
    __builtin_amdgcn_s_setprio(1);
#pragma unroll
    for (int mb = 0; mb < 4; ++mb)
#pragma unroll
      for (int nbq = 0; nbq < 2; ++nbq) {
        floatx4 acc = (floatx4){0.f, 0.f, 0.f, 0.f};
        acc = __builtin_amdgcn_mfma_f32_16x16x32_bf16(F.k[mb][0], qf[nbq][0], acc, 0, 0, 0);
        acc = __builtin_amdgcn_mfma_f32_16x16x32_bf16(F.k[mb][1], qf[nbq][1], acc, 0, 0, 0);
        sacc[mb][nbq] = acc;
      }
    __builtin_amdgcn_s_setprio(0);

    // softmax: exp2 + cvt_pk + permlane -> PV A-frags (verified r11 mapping)
    bf16x8 pa[2][2];
#pragma unroll
    for (int nbq = 0; nbq < 2; ++nbq) {
#pragma unroll
      for (int pp = 0; pp < 2; ++pp) {
        float e00 = __builtin_amdgcn_exp2f(sacc[2 * pp][nbq][0]);
        float e01 = __builtin_amdgcn_exp2f(sacc[2 * pp][nbq][1]);
        float e02 = __builtin_amdgcn_exp2f(sacc[2 * pp][nbq][2]);
        float e03 = __builtin_amdgcn_exp2f(sacc[2 * pp][nbq][3]);
        float e10 = __builtin_amdgcn_exp2f(sacc[2 * pp + 1][nbq][0]);
        float e11 = __builtin_amdgcn_exp2f(sacc[2 * pp + 1][nbq][1]);
        float e12 = __builtin_amdgcn_exp2f(sacc[2 * pp + 1][nbq][2]);
        float e13 = __builtin_amdgcn_exp2f(sacc[2 * pp + 1][nbq][3]);
        lsum_[nbq] +=
            (((e00 + e01) + (e02 + e03)) + ((e10 + e11) + (e12 + e13)));
        unsigned int w00, w01, w10, w11;
        asm("v_cvt_pk_bf16_f32 %0, %1, %2" : "=v"(w00) : "v"(e00), "v"(e01));
        asm("v_cvt_pk_bf16_f32 %0, %1, %2" : "=v"(w01) : "v"(e02), "v"(e03));
        asm("v_cvt_pk_bf16_f32 %0, %1, %2" : "=v"(w10) : "v"(e10), "v"(e11));
        asm("v_cvt_pk_bf16_f32 %0, %1, %2" : "=v"(w11) : "v"(e12), "v"(e13));
        auto sa = __builtin_amdgcn_permlane32_swap(w00, w10, false, false);
        auto xa = __builtin_amdgcn_permlane16_swap(sa[0], sa[1], false, false);
        auto sb = __builtin_amdgcn_permlane32_swap(w01, w11, false, false);
        auto xb = __builtin_amdgcn_permlane16_swap(sb[0], sb[1], false, false);
        union { unsigned int u[4]; bf16x8 v; } pk_;
        pk_.u[0] = xa[0]; pk_.u[1] = xb[0]; pk_.u[2] = xa[1]; pk_.u[3] = xb[1];
        pa[nbq][pp] = pk_.v;
      }
    }

    // PV MFMA cluster
    __builtin_amdgcn_s_setprio(1);
#pragma unroll
    for (int nbd = 0; nbd < 4; ++nbd)
#pragma unroll
      for (int mbq = 0; mbq < 2; ++mbq) {
        oacc[mbq][nbd] = __builtin_amdgcn_mfma_f32_16x16x32_bf16(
            pa[mbq][0], F.v[nbd][0], oacc[mbq][nbd], 0, 0, 0);
        oacc[mbq][nbd] = __builtin_amdgcn_mfma_f32_16x16x32_bf16(
            pa[mbq][1], F.v[nbd][1], oacc[mbq][nbd], 0, 0, 0);
      }
    __builtin_amdgcn_s_setprio(0);
  };

  // ---- main loop: 32 chunks of 64 s, register double-buffer, no barriers.
  Frags FA, FB;
  load_frags(FA, 0);
  for (int t = 0; t < 32; t += 2) {
    load_frags(FB, t + 1);        // prefetch odd chunk (full body of cover)
    compute(FA);
    if (t + 2 < 32) load_frags(FA, t + 2);  // prefetch next even chunk
    compute(FB);
  }

  // ---- epilogue: wave-local. lsum: cross-quad reduce, per-row bcast ----
  float li[2][4];
#pragma unroll
  for (int mbq = 0; mbq < 2; ++mbq) {
    float t = lsum_[mbq];
    t += __shfl_xor(t, 16, 64);
    t += __shfl_xor(t, 32, 64);
#pragma unroll
    for (int r = 0; r < 4; ++r)
      li[mbq][r] = 1.f / __shfl(t, quad * 4 + r, 64);
  }

  // oacc: lane(l16,quad) reg r = O[q = qrow0+mbq*16+quad*4+r][d = nbd*16+l16]
#pragma unroll
  for (int mbq = 0; mbq < 2; ++mbq)
#pragma unroll
    for (int nbd = 0; nbd < 4; ++nbd)
#pragma unroll
      for (int r = 0; r < 4; ++r)
        Og[(((size_t)n * L_ + qrow0 + mbq * 16 + quad * 4 + r) * H_ + h) * D_ +
           nbd * 16 + l16] = oacc[mbq][nbd][r] * li[mbq][r];
}

// ---------------------------------------------------------------------------
extern "C" void kernel_launch(void* const* d_in, const int* in_sizes, int n_in,
                              void* d_out, int out_size, void* d_ws, size_t ws_size,
                              hipStream_t stream) {
  const float* Q = (const float*)d_in[0];
  const float* K = (const float*)d_in[1];
  const float* V = (const float*)d_in[2];
  float* O = (float*)d_out;

  bf16_t* Kb  = (bf16_t*)d_ws;                   // [nh][s][d] bf16
  bf16_t* Vtb = Kb + (size_t)N_ * H_ * S_ * D_;  // [nh][d][s] bf16

  prep<<<dim3(S_ / 64, N_ * H_), 256, 0, stream>>>(K, V, Kb, Vtb);
  fattn<<<dim3(256, 1), 512, 0, stream>>>(Q, Kb, Vtb, O);
}

// Round 10
// 133.912 us; speedup vs baseline: 1.5991x; 1.5991x over previous
//
#include <hip/hip_runtime.h>
#include <hip/hip_bf16.h>
#include <math.h>

typedef __bf16 bf16_t;
typedef __bf16 bf16x2 __attribute__((ext_vector_type(2)));
typedef __bf16 bf16x4 __attribute__((ext_vector_type(4)));
typedef __bf16 bf16x8 __attribute__((ext_vector_type(8)));
typedef float floatx4 __attribute__((ext_vector_type(4)));

constexpr int N_ = 4, L_ = 2048, S_ = 2048, H_ = 8, D_ = 64;

// async global->LDS, 16B/lane; LDS dest = wave-uniform base + lane*16
__device__ __forceinline__ void async_load16(const void* g, void* l) {
  __builtin_amdgcn_global_load_lds(
      (const __attribute__((address_space(1))) void*)g,
      (__attribute__((address_space(3))) void*)l, 16, 0, 0);
}

// ---------------------------------------------------------------------------
// prologue: K fp32 [n,s,h,d] -> bf16 Kb [nh,s,d]; V fp32 -> bf16 Vtb [nh,d,s]
__global__ __launch_bounds__(256)
void prep(const float* __restrict__ Kg, const float* __restrict__ Vg,
          bf16_t* __restrict__ Kb, bf16_t* __restrict__ Vtb) {
  __shared__ bf16x2 pr_sh[64 * 33];
  const int tid = threadIdx.x;
  const int nh = blockIdx.y, s0 = blockIdx.x * 64;
  const int n = nh >> 3, h = nh & 7;
  {
    const int srow = tid >> 2, d0 = (tid & 3) * 16;
    const float* kp = Kg + (((size_t)n * S_ + s0 + srow) * H_ + h) * D_ + d0;
    float4 x0 = ((const float4*)kp)[0], x1 = ((const float4*)kp)[1];
    float4 x2 = ((const float4*)kp)[2], x3 = ((const float4*)kp)[3];
    bf16x8 f0, f1;
    f0[0] = (bf16_t)x0.x; f0[1] = (bf16_t)x0.y; f0[2] = (bf16_t)x0.z; f0[3] = (bf16_t)x0.w;
    f0[4] = (bf16_t)x1.x; f0[5] = (bf16_t)x1.y; f0[6] = (bf16_t)x1.z; f0[7] = (bf16_t)x1.w;
    f1[0] = (bf16_t)x2.x; f1[1] = (bf16_t)x2.y; f1[2] = (bf16_t)x2.z; f1[3] = (bf16_t)x2.w;
    f1[4] = (bf16_t)x3.x; f1[5] = (bf16_t)x3.y; f1[6] = (bf16_t)x3.z; f1[7] = (bf16_t)x3.w;
    *(bf16x8*)&Kb[((size_t)nh * S_ + s0 + srow) * D_ + d0] = f0;
    *(bf16x8*)&Kb[((size_t)nh * S_ + s0 + srow) * D_ + d0 + 8] = f1;
  }
  {
    const int s2 = tid >> 3;
    const int dg = (tid & 7) * 8;
    const float* vp0 = Vg + (((size_t)n * S_ + s0 + 2 * s2) * H_ + h) * D_ + dg;
    const float* vp1 = vp0 + (size_t)H_ * D_;
    float4 a0 = ((const float4*)vp0)[0], a1 = ((const float4*)vp0)[1];
    float4 b0 = ((const float4*)vp1)[0], b1 = ((const float4*)vp1)[1];
    float r0[8] = { a0.x, a0.y, a0.z, a0.w, a1.x, a1.y, a1.z, a1.w };
    float r1[8] = { b0.x, b0.y, b0.z, b0.w, b1.x, b1.y, b1.z, b1.w };
#pragma unroll
    for (int j = 0; j < 8; ++j) {
      bf16x2 pr; pr[0] = (bf16_t)r0[j]; pr[1] = (bf16_t)r1[j];
      pr_sh[(dg + j) * 33 + s2] = pr;
    }
  }
  __syncthreads();
  {
    const int dr = tid >> 2, sq = tid & 3;
    bf16x8 o0, o1;
#pragma unroll
    for (int p = 0; p < 4; ++p) {
      bf16x2 v = pr_sh[dr * 33 + sq * 8 + p];
      o0[2 * p] = v[0]; o0[2 * p + 1] = v[1];
    }
#pragma unroll
    for (int p = 0; p < 4; ++p) {
      bf16x2 v = pr_sh[dr * 33 + sq * 8 + 4 + p];
      o1[2 * p] = v[0]; o1[2 * p + 1] = v[1];
    }
    bf16_t* op = &Vtb[((size_t)nh * D_ + dr) * S_ + s0 + sq * 16];
    *(bf16x8*)op = o0;
    *(bf16x8*)(op + 8) = o1;
  }
}

// ---------------------------------------------------------------------------
// fattn r19: one-back PV pipeline on r14 geometry. r18 (LDS-free) regressed
// 2.5x -> LDS transport restored. Audit of r12-r17 vs r0: every kernel
// since r12 ran QK->sm->PV serial within a chunk (r0 pipelined PV one back)
// — each chunk's 620-cyc MFMA block gated on the previous chunk's VALU
// chain = the invariant 49-55us plateau. Fix: per chunk t:
//   K-reads(t) -> [QK(t) + PV(t-1)] one prio-1 MFMA cluster
//   -> V-reads(t) -> sm(t) (prio 0; result not needed until after the
//   NEXT chunk's MFMA cluster -> VALU/trans hides under MFMA).
// paP/vfP carried in registers; V-reads placed after PV(t-1) so the V
// live-set never doubles. Pair loop restructured as 8 x (two inlined
// pair-bodies with COMPILE-TIME smem bases) -> ds_read addrs become
// hoisted-VGPR + imm-offset, deleting per-chunk address VALU (was ~1/3 of
// VALUBusy). Safety: with register carries, reads no longer drain
// implicitly pre-barrier -> explicit lgkmcnt(0) added before each pair
// barrier (restores the r14 stage-overwrite proof). Geometry unchanged:
// 256 blocks, 512 thr, 32q/wave, 64KB pair-dbuf, vmcnt(0)+s_barrier/pair.
__global__ __launch_bounds__(512, 2)
void fattn(const float* __restrict__ Qg, const bf16_t* __restrict__ Kb,
           const bf16_t* __restrict__ Vtb, float* __restrict__ Og) {
  __shared__ __align__(16) char smem[65536];  // 2 pairs x (2 x (8KB K+8KB V))

  const int tid  = threadIdx.x;
  const int wave = tid >> 6;
  const int lane = tid & 63;
  const int quad = lane >> 4;
  const int l16  = lane & 15;

  // XCD mapping: 256 blocks, lb&7 = XCD; nh = lb&31 -> nh's 8 q-blocks all
  // on XCD nh&7; each XCD holds 4 nh x 1MB K/V = exactly its 4MB L2.
  const int lb = blockIdx.x;
  const int nh = lb & 31;
  const int qb = lb >> 5;                    // 0..7
  const int n  = nh >> 3;
  const int h  = nh & 7;
  const int qrow0 = qb * 256 + wave * 32;    // wave owns 32 q rows

  // ---- Q B-frags (B[k=d][n=q]: n=l16, k=quad*8+j), scale*log2e folded ----
  const float qs = 0.125f * 1.44269504088896340736f;
  bf16x8 qf[2][2];
#pragma unroll
  for (int nbq = 0; nbq < 2; ++nbq)
#pragma unroll
    for (int kc = 0; kc < 2; ++kc) {
      const float* p = Qg +
          (((size_t)n * L_ + qrow0 + nbq * 16 + l16) * H_ + h) * D_ +
          kc * 32 + quad * 8;
      float4 a = ((const float4*)p)[0];
      float4 b = ((const float4*)p)[1];
      bf16x8 f;
      f[0] = (bf16_t)(a.x * qs); f[1] = (bf16_t)(a.y * qs);
      f[2] = (bf16_t)(a.z * qs); f[3] = (bf16_t)(a.w * qs);
      f[4] = (bf16_t)(b.x * qs); f[5] = (bf16_t)(b.y * qs);
      f[6] = (bf16_t)(b.z * qs); f[7] = (bf16_t)(b.w * qs);
      qf[nbq][kc] = f;
    }

  floatx4 oacc[2][4];
#pragma unroll
  for (int a = 0; a < 2; ++a)
#pragma unroll
    for (int b = 0; b < 4; ++b) oacc[a][b] = (floatx4){0.f, 0.f, 0.f, 0.f};
  float lsum_[2] = {0.f, 0.f};

  const bf16_t* kbase = Kb + (size_t)nh * S_ * D_;
  const bf16_t* vbase = Vtb + (size_t)nh * D_ * S_;

  // DMA lane constants: row-in-group = lane>>3, XOR-swizzled 16B chunk.
  const int rr  = lane >> 3;
  const int cc8 = ((lane & 7) ^ (lane >> 3)) * 8;

  // prime pair 0 with chunks {0, 64} (4 loads per wave)
  {
    async_load16(kbase + (size_t)(0 + wave * 8 + rr) * 64 + cc8,
                 smem + wave * 1024);
    async_load16(vbase + (size_t)(wave * 8 + rr) * S_ + 0 + cc8,
                 smem + 8192 + wave * 1024);
    async_load16(kbase + (size_t)(64 + wave * 8 + rr) * 64 + cc8,
                 smem + 16384 + wave * 1024);
    async_load16(vbase + (size_t)(wave * 8 + rr) * S_ + 64 + cc8,
                 smem + 24576 + wave * 1024);
  }

  // pipelined-PV carry state (zero -> chunk 0's PV is a no-op add)
  bf16x8 zf;
#pragma unroll
  for (int i = 0; i < 8; ++i) zf[i] = (bf16_t)0.0f;
  bf16x8 paP[2][2] = {{zf, zf}, {zf, zf}};
  bf16x8 vfP[4][2] = {{zf, zf}, {zf, zf}, {zf, zf}, {zf, zf}};

  // ---- one chunk: K reads; [QK(t) + PV(t-1)] MFMA cluster; V reads(t);
  //      softmax(t) -> paP. vfP consumed (PV) before being overwritten. ----
  auto chunk_body = [&](const bf16_t* kbufj, const bf16_t* vbufj) {
    // K A-frags (compiler inserts counted lgkmcnt before QK)
    bf16x8 kf[4][2];
#pragma unroll
    for (int mb = 0; mb < 4; ++mb) {
      kf[mb][0] = *(const bf16x8*)
          &kbufj[(mb * 16 + l16) * 64 + ((quad ^ (l16 & 7)) * 8)];
      kf[mb][1] = *(const bf16x8*)
          &kbufj[(mb * 16 + l16) * 64 + (((4 + quad) ^ (l16 & 7)) * 8)];
    }

    floatx4 sacc[4][2];
    __builtin_amdgcn_s_setprio(1);
    // QK(t)
#pragma unroll
    for (int mb = 0; mb < 4; ++mb)
#pragma unroll
      for (int nbq = 0; nbq < 2; ++nbq) {
        floatx4 acc = (floatx4){0.f, 0.f, 0.f, 0.f};
        acc = __builtin_amdgcn_mfma_f32_16x16x32_bf16(kf[mb][0], qf[nbq][0], acc, 0, 0, 0);
        acc = __builtin_amdgcn_mfma_f32_16x16x32_bf16(kf[mb][1], qf[nbq][1], acc, 0, 0, 0);
        sacc[mb][nbq] = acc;
      }
    // PV(t-1): register-carried operands, independent of QK(t)
#pragma unroll
    for (int nbd = 0; nbd < 4; ++nbd)
#pragma unroll
      for (int mbq = 0; mbq < 2; ++mbq) {
        oacc[mbq][nbd] = __builtin_amdgcn_mfma_f32_16x16x32_bf16(
            paP[mbq][0], vfP[nbd][0], oacc[mbq][nbd], 0, 0, 0);
        oacc[mbq][nbd] = __builtin_amdgcn_mfma_f32_16x16x32_bf16(
            paP[mbq][1], vfP[nbd][1], oacc[mbq][nbd], 0, 0, 0);
      }
    __builtin_amdgcn_s_setprio(0);

    // V B-frags for THIS chunk (consumed by next chunk's PV)
#pragma unroll
    for (int nbd = 0; nbd < 4; ++nbd) {
      vfP[nbd][0] = *(const bf16x8*)
          &vbufj[(nbd * 16 + l16) * 64 + ((quad ^ (l16 & 7)) * 8)];
      vfP[nbd][1] = *(const bf16x8*)
          &vbufj[(nbd * 16 + l16) * 64 + (((4 + quad) ^ (l16 & 7)) * 8)];
    }

    // softmax(t): exp2 + cvt_pk + permlane -> paP (verified r11 mapping);
    // result not needed until after the NEXT chunk's MFMA cluster.
#pragma unroll
    for (int nbq = 0; nbq < 2; ++nbq) {
#pragma unroll
      for (int pp = 0; pp < 2; ++pp) {
        float e00 = __builtin_amdgcn_exp2f(sacc[2 * pp][nbq][0]);
        float e01 = __builtin_amdgcn_exp2f(sacc[2 * pp][nbq][1]);
        float e02 = __builtin_amdgcn_exp2f(sacc[2 * pp][nbq][2]);
        float e03 = __builtin_amdgcn_exp2f(sacc[2 * pp][nbq][3]);
        float e10 = __builtin_amdgcn_exp2f(sacc[2 * pp + 1][nbq][0]);
        float e11 = __builtin_amdgcn_exp2f(sacc[2 * pp + 1][nbq][1]);
        float e12 = __builtin_amdgcn_exp2f(sacc[2 * pp + 1][nbq][2]);
        float e13 = __builtin_amdgcn_exp2f(sacc[2 * pp + 1][nbq][3]);
        lsum_[nbq] +=
            (((e00 + e01) + (e02 + e03)) + ((e10 + e11) + (e12 + e13)));
        unsigned int w00, w01, w10, w11;
        asm("v_cvt_pk_bf16_f32 %0, %1, %2" : "=v"(w00) : "v"(e00), "v"(e01));
        asm("v_cvt_pk_bf16_f32 %0, %1, %2" : "=v"(w01) : "v"(e02), "v"(e03));
        asm("v_cvt_pk_bf16_f32 %0, %1, %2" : "=v"(w10) : "v"(e10), "v"(e11));
        asm("v_cvt_pk_bf16_f32 %0, %1, %2" : "=v"(w11) : "v"(e12), "v"(e13));
        auto sa = __builtin_amdgcn_permlane32_swap(w00, w10, false, false);
        auto xa = __builtin_amdgcn_permlane16_swap(sa[0], sa[1], false, false);
        auto sb = __builtin_amdgcn_permlane32_swap(w01, w11, false, false);
        auto xb = __builtin_amdgcn_permlane16_swap(sb[0], sb[1], false, false);
        union { unsigned int u[4]; bf16x8 v; } pk_;
        pk_.u[0] = xa[0]; pk_.u[1] = xb[0]; pk_.u[2] = xa[1]; pk_.u[3] = xb[1];
        paP[nbq][pp] = pk_.v;
      }
    }
  };

  // ---- pair body with compile-time LDS bases (imm-offset ds_reads) ----
  auto pair_body = [&](char* cur, char* nxt, int p) {
    // stage loads for this pair (issued a full pair ago) + ALL our ds_reads
    // of the other pair drained (required: vfP carries span the barrier).
    asm volatile("s_waitcnt vmcnt(0) lgkmcnt(0)" ::: "memory");
    __builtin_amdgcn_s_barrier();
    if (p < 15) {
      const int s0 = (p + 1) * 128;
      async_load16(kbase + (size_t)(s0 + wave * 8 + rr) * 64 + cc8,
                   nxt + wave * 1024);
      async_load16(vbase + (size_t)(wave * 8 + rr) * S_ + s0 + cc8,
                   nxt + 8192 + wave * 1024);
      async_load16(kbase + (size_t)(s0 + 64 + wave * 8 + rr) * 64 + cc8,
                   nxt + 16384 + wave * 1024);
      async_load16(vbase + (size_t)(wave * 8 + rr) * S_ + s0 + 64 + cc8,
                   nxt + 24576 + wave * 1024);
    }
    chunk_body((const bf16_t*)cur, (const bf16_t*)(cur + 8192));
    chunk_body((const bf16_t*)(cur + 16384), (const bf16_t*)(cur + 24576));
  };

  for (int pp = 0; pp < 8; ++pp) {
    pair_body(smem, smem + 32768, 2 * pp);          // even pair -> buf0
    pair_body(smem + 32768, smem, 2 * pp + 1);      // odd pair  -> buf1
  }

  // ---- drain: PV(chunk 31) ----
  __builtin_amdgcn_s_setprio(1);
#pragma unroll
  for (int nbd = 0; nbd < 4; ++nbd)
#pragma unroll
    for (int mbq = 0; mbq < 2; ++mbq) {
      oacc[mbq][nbd] = __builtin_amdgcn_mfma_f32_16x16x32_bf16(
          paP[mbq][0], vfP[nbd][0], oacc[mbq][nbd], 0, 0, 0);
      oacc[mbq][nbd] = __builtin_amdgcn_mfma_f32_16x16x32_bf16(
          paP[mbq][1], vfP[nbd][1], oacc[mbq][nbd], 0, 0, 0);
    }
  __builtin_amdgcn_s_setprio(0);

  // ---- epilogue: wave-local. lsum: cross-quad reduce, per-row bcast ----
  float li[2][4];
#pragma unroll
  for (int mbq = 0; mbq < 2; ++mbq) {
    float t = lsum_[mbq];
    t += __shfl_xor(t, 16, 64);
    t += __shfl_xor(t, 32, 64);
#pragma unroll
    for (int r = 0; r < 4; ++r)
      li[mbq][r] = 1.f / __shfl(t, quad * 4 + r, 64);
  }

  // oacc: lane(l16,quad) reg r = O[q = qrow0+mbq*16+quad*4+r][d = nbd*16+l16]
#pragma unroll
  for (int mbq = 0; mbq < 2; ++mbq)
#pragma unroll
    for (int nbd = 0; nbd < 4; ++nbd)
#pragma unroll
      for (int r = 0; r < 4; ++r)
        Og[(((size_t)n * L_ + qrow0 + mbq * 16 + quad * 4 + r) * H_ + h) * D_ +
           nbd * 16 + l16] = oacc[mbq][nbd][r] * li[mbq][r];
}

// ---------------------------------------------------------------------------
extern "C" void kernel_launch(void* const* d_in, const int* in_sizes, int n_in,
                              void* d_out, int out_size, void* d_ws, size_t ws_size,
                              hipStream_t stream) {
  const float* Q = (const float*)d_in[0];
  const float* K = (const float*)d_in[1];
  const float* V = (const float*)d_in[2];
  float* O = (float*)d_out;

  bf16_t* Kb  = (bf16_t*)d_ws;                   // [nh][s][d] bf16
  bf16_t* Vtb = Kb + (size_t)N_ * H_ * S_ * D_;  // [nh][d][s] bf16

  prep<<<dim3(S_ / 64, N_ * H_), 256, 0, stream>>>(K, V, Kb, Vtb);
  fattn<<<dim3(256, 1), 512, 0, stream>>>(Q, Kb, Vtb, O);
}